// Round 14
// baseline (604.890 us; speedup 1.0000x reference)
//
#include <hip/hip_runtime.h>
#include <stdint.h>
#include <stddef.h>

typedef unsigned short u16;
typedef unsigned int u32;
typedef unsigned long long u64;
typedef __attribute__((ext_vector_type(4))) int i32x4;
typedef __attribute__((ext_vector_type(16))) int i32x16;
typedef __attribute__((ext_vector_type(4))) float f32x4;

#define NPOS 8192      // B*H*W
#define MROW 16384     // M
#define CDIM 1024      // C
#define QS 25.4f       // int8 quant scale (clip at ~5 sigma: essentially never)

__device__ __forceinline__ u32 fkey(float f){   // order-preserving float->uint
  union { float f; u32 u; } z; z.f = f;
  u32 b = z.u;
  return b ^ ((b & 0x80000000u) ? 0xffffffffu : 0x80000000u);
}
__device__ __forceinline__ float unfkey(u32 u){
  u32 b = (u & 0x80000000u) ? (u ^ 0x80000000u) : ~u;
  union { u32 u; float f; } z; z.u = b; return z.f;
}
__device__ __forceinline__ u64 umin64(u64 a, u64 b){ return a < b ? a : b; }
__device__ __forceinline__ u64 umax64(u64 a, u64 b){ return a > b ? a : b; }
__device__ __forceinline__ float wave_sum(float v){
  #pragma unroll
  for(int o = 32; o; o >>= 1) v += __shfl_xor(v, o, 64);
  return v;
}
__device__ __forceinline__ int q8(float x){     // signed i8 code, low 8 bits
  float y = fminf(fmaxf(x * QS, -127.f), 127.f);
  return __float2int_rn(y) & 0xff;
}

// async global->LDS, 16B per lane (wave-uniform LDS base + lane*16; global addr is per-lane)
__device__ __forceinline__ void gload16(const void* g, void* l){
  __builtin_amdgcn_global_load_lds((const __attribute__((address_space(1))) u32*)g,
                                   (__attribute__((address_space(3))) u32*)l, 16, 0, 0);
}

// ---- K1 (fused prep): blocks [0,4096): 4 mb rows per block, wave-per-row -> mq i8 + m_sq;
//      blocks [4096, 6144): feature transpose -> fT (N,C) fp32 + fq (N,C) i8, float4 both sides ----
__global__ __launch_bounds__(256) void k_prep(const float* __restrict__ mb, const float* __restrict__ feat,
                                              signed char* __restrict__ mq, signed char* __restrict__ fq,
                                              float* __restrict__ fT, float* __restrict__ m_sq,
                                              u32* __restrict__ minmax){
  __shared__ float tile[64][65];
  int bid = blockIdx.x, t = threadIdx.x;
  if(bid < 4096){
    int lane = t & 63, w = t >> 6;
    int row = bid * 4 + w;
    if(row == 0 && lane == 0){ minmax[0] = 0x7f800000u; minmax[1] = 0u; }
    const float4* src = (const float4*)(mb + (size_t)row * CDIM);
    u32* dst = (u32*)(mq + (size_t)row * CDIM);
    float s = 0.f;
    #pragma unroll
    for(int ch = 0; ch < 4; ch++){
      float4 v = src[ch * 64 + lane];
      u32 packed = (u32)q8(v.x) | ((u32)q8(v.y) << 8) | ((u32)q8(v.z) << 16) | ((u32)q8(v.w) << 24);
      dst[ch * 64 + lane] = packed;
      s += v.x*v.x + v.y*v.y + v.z*v.z + v.w*v.w;
    }
    s = wave_sum(s);
    if(lane == 0) m_sq[row] = s;
  } else {
    int e = bid - 4096;                 // 0..2047
    int b = e >> 8, c0 = ((e >> 4) & 15) * 64, hw0 = (e & 15) * 64;
    // load: feat[b][c0+cL][hw0+quad] -> tile[cL][hw] (float4 over hw, coalesced)
    #pragma unroll 4
    for(int r = 0; r < 4; r++){
      int li = r * 256 + t;             // 0..1023
      int cL = li >> 4, q = li & 15;
      float4 v = *((const float4*)(feat + ((size_t)b * CDIM + c0 + cL) * 1024 + hw0) + q);
      tile[cL][q * 4 + 0] = v.x; tile[cL][q * 4 + 1] = v.y;
      tile[cL][q * 4 + 2] = v.z; tile[cL][q * 4 + 3] = v.w;
    }
    __syncthreads();
    // store: fT[n][c] float4 over c + fq packed u32 (both coalesced)
    #pragma unroll 4
    for(int r = 0; r < 4; r++){
      int li = r * 256 + t;
      int hwL = li >> 4, q = li & 15;
      float4 v;
      v.x = tile[q * 4 + 0][hwL]; v.y = tile[q * 4 + 1][hwL];
      v.z = tile[q * 4 + 2][hwL]; v.w = tile[q * 4 + 3][hwL];
      int n = b * 1024 + hw0 + hwL;
      int c = c0 + q * 4;
      *((float4*)(fT + (size_t)n * CDIM + c)) = v;
      u32 packed = (u32)q8(v.x) | ((u32)q8(v.y) << 8) | ((u32)q8(v.z) << 16) | ((u32)q8(v.w) << 24);
      *((u32*)(fq + (size_t)n * CDIM + c)) = packed;
    }
  }
}

__device__ __forceinline__ i32x16 mfma32_i8(i32x4 a, i32x4 b, i32x16 c){
  return __builtin_amdgcn_mfma_i32_32x32x32_i8(a, b, c, 0, 0, 0);
}

// ---- K4: int8 GEMM, 256x256 tile, 8 waves (2x4), per-wave 128x64, BK=128 (i8),
//          2 LDS buffers (128KB), 8 sync-drains. MFMA shape 32x32x32 (4404 TOPS ubench
//          vs 3944 for 16x16x64; 2x OPS/instr halves issue pressure at 2 waves/SIMD).
//          acc = 8 x i32x16 = 128 regs (same as before). Staging/swizzle verbatim R13.
//          A-frag: row = wm*128+mi*32+(lane&31), k-chunk kc: byte slot (kc*2+(lane>>5))
//          XOR (row&7). C/D mapping (HW-verified): col=lane&31, row=(r&3)+8*(r>>2)+4*(lane>>5). ----
__global__ __launch_bounds__(512, 2) void k_gemm(const signed char* __restrict__ fq, const signed char* __restrict__ mq,
                                                 const float* __restrict__ m_sq, u64* __restrict__ cand){
  __shared__ unsigned char lds[2][2][256][128];   // 128 KB
  int bid = blockIdx.x;
  int ct = (bid & 7) * 8 + ((bid >> 3) & 7);   // XCD-chunked: XCD k owns ct in [8k, 8k+8)
  int rt = bid >> 6;                           // 0..31
  int t = threadIdx.x, lane = t & 63, wid = t >> 6;
  int wm = wid >> 2, wn = wid & 3;        // wave tile: rows wm*128, cols wn*64
  int cl = lane & 31, h = lane >> 5;      // fragment row/col sel (32x32) / k-half sel
  int sr = t >> 3, sl = t & 7;            // staging: 8 slots per 128B row, 64 rows per round

  // loop-carried global staging pointers (advance +128 per staged K-tile)
  int ssw = (sl ^ (sr & 7)) * 16;         // inverse swizzle on SOURCE ((sr+64k)&7 == sr&7)
  const signed char* pA = fq + (size_t)(rt * 256 + sr) * CDIM + ssw;
  const signed char* pB = mq + (size_t)(ct * 256 + sr) * CDIM + ssw;
  unsigned char* Ld = &lds[0][0][sr][sl * 16];          // buf adds literal b*65536; B adds 32768
  // thread-constant fragment slot byte-offsets for the 4 k-chunks (K=32 each) of BK=128
  int fsw[4];
  #pragma unroll
  for(int kc = 0; kc < 4; kc++) fsw[kc] = ((kc * 2 + h) ^ (lane & 7)) * 16;
  const unsigned char* La = &lds[0][0][wm * 128 + cl][0];   // A: + mi*4096 + fsw[kc]
  const unsigned char* Lb = &lds[0][1][wn * 64  + cl][0];   // B: + ni*4096 + fsw[kc]

  i32x16 acc[4][2];
  #pragma unroll
  for(int i = 0; i < 4; i++)
    #pragma unroll
    for(int j = 0; j < 2; j++)
      #pragma unroll
      for(int r = 0; r < 16; r++) acc[i][j][r] = 0;

#define STAGE(BUF) do{ \
    _Pragma("unroll") for(int r_ = 0; r_ < 4; r_++) \
      gload16(pA + (size_t)(r_ * 64) * CDIM, Ld + (BUF) * 65536 + r_ * 8192); \
    _Pragma("unroll") for(int r_ = 0; r_ < 4; r_++) \
      gload16(pB + (size_t)(r_ * 64) * CDIM, Ld + (BUF) * 65536 + 32768 + r_ * 8192); \
    pA += 128; pB += 128; \
  }while(0)

#define COMPUTE(BUF) do{ \
    _Pragma("unroll") for(int kc_ = 0; kc_ < 4; kc_++){ \
      i32x4 fb0 = *(const i32x4*)(Lb + (BUF) * 65536 + fsw[kc_]); \
      i32x4 fb1 = *(const i32x4*)(Lb + (BUF) * 65536 + 4096 + fsw[kc_]); \
      _Pragma("unroll") for(int mi_ = 0; mi_ < 4; mi_++){ \
        i32x4 fa = *(const i32x4*)(La + (BUF) * 65536 + mi_ * 4096 + fsw[kc_]); \
        acc[mi_][0] = mfma32_i8(fa, fb0, acc[mi_][0]); \
        acc[mi_][1] = mfma32_i8(fa, fb1, acc[mi_][1]); \
      } \
    } \
  }while(0)

#define SYNC0() asm volatile("s_waitcnt vmcnt(0) lgkmcnt(0)\n\ts_barrier" ::: "memory")

  STAGE(0);
  SYNC0();
  for(int it = 0; it < 3; ++it){
    STAGE(1); COMPUTE(0); SYNC0();
    STAGE(0); COMPUTE(1); SYNC0();
  }
  STAGE(1); COMPUTE(0); SYNC0();   // K-tile 6 (stage tile 7)
  COMPUTE(1);                      // K-tile 7

#undef STAGE
#undef COMPUTE
#undef SYNC0

  // ---- epilogue: per-row TOP-2 of (m_sq[col] - 2*cross) over this block's 256 cols ----
  // lane holds cols {wn*64 + ni*32 + cl}; reg r of acc[mi][ni] is row wm*128+mi*32+(r&3)+8*(r>>2)+4*h
  const float SI = 2.0f / (QS * QS);
  float msqv[2];
  msqv[0] = m_sq[ct * 256 + wn * 64 + cl];
  msqv[1] = m_sq[ct * 256 + wn * 64 + 32 + cl];
  __syncthreads();                          // all LDS reads done; safe to reuse as scratch
  u64* rl = (u64*)&lds[0][0][0][0];         // [wn][256 rows][2] = 16KB
  #pragma unroll
  for(int mi = 0; mi < 4; mi++){
    #pragma unroll
    for(int r = 0; r < 16; r++){
      float v0 = msqv[0] - SI * (float)acc[mi][0][r];
      float v1 = msqv[1] - SI * (float)acc[mi][1][r];
      u64 key0 = ((u64)fkey(v0) << 32) | (u32)(ct * 256 + wn * 64 + cl);
      u64 key1 = ((u64)fkey(v1) << 32) | (u32)(ct * 256 + wn * 64 + 32 + cl);
      u64 k1 = umin64(key0, key1), k2 = umax64(key0, key1);
      #pragma unroll
      for(int m = 1; m < 32; m <<= 1){      // butterfly top-2 merge within each 32-lane half
        u64 o1 = __shfl_xor(k1, m, 64), o2 = __shfl_xor(k2, m, 64);
        u64 n1 = umin64(k1, o1);
        u64 n2 = umin64(umax64(k1, o1), umin64(k2, o2));
        k1 = n1; k2 = n2;
      }
      if(cl == 0){                          // lanes 0 and 32 write their half's row
        int rowl = wm * 128 + mi * 32 + (r & 3) + 8 * (r >> 2) + 4 * h;
        rl[(wn * 256 + rowl) * 2 + 0] = k1;
        rl[(wn * 256 + rowl) * 2 + 1] = k2;
      }
    }
  }
  __syncthreads();
  if(t < 256){
    u64 a1 = rl[t * 2], a2 = rl[t * 2 + 1];
    #pragma unroll
    for(int w = 1; w < 4; w++){
      u64 b1 = rl[(w * 256 + t) * 2], b2 = rl[(w * 256 + t) * 2 + 1];
      u64 n1 = umin64(a1, b1);
      u64 n2 = umin64(umax64(a1, b1), umin64(a2, b2));
      a1 = n1; a2 = n2;
    }
    size_t base = ((size_t)(rt * 256 + t)) * 128 + ct * 2;
    cand[base] = a1; cand[base + 1] = a2;
  }
}

// ---- K5: wave-per-row finalize, zero barriers. Top-2/top-4 of 128 keys via u64 wave
//          butterflies; exact fp32 recheck (1 or 4 cands by margin); influence ----
__global__ __launch_bounds__(256) void k_finalize(const u64* __restrict__ cand,
    const float* __restrict__ fT,
    const float* __restrict__ mb, const float* __restrict__ m_sq,
    float* __restrict__ inf_arr, u32* __restrict__ minmax){
  int t = threadIdx.x, lane = t & 63, w = t >> 6;
  int n = blockIdx.x * 4 + w;
  const u64* cr = cand + (size_t)n * 128;
  u64 a = cr[lane * 2], b = cr[lane * 2 + 1];
  u64 k1 = umin64(a, b), k2 = umax64(a, b);
  #pragma unroll
  for(int m = 1; m < 64; m <<= 1){          // wave butterfly top-2 merge (all lanes converge)
    u64 o1 = __shfl_xor(k1, m, 64), o2 = __shfl_xor(k2, m, 64);
    u64 n1 = umin64(k1, o1);
    u64 n2 = umin64(umax64(k1, o1), umin64(k2, o2));
    k1 = n1; k2 = n2;
  }
  float v1 = unfkey((u32)(k1 >> 32)), v2 = unfkey((u32)(k2 >> 32));
  // margin: approx-dist2 gap; i8 quant err sigma ~1.46 pairwise -> 10 is ~6.8 sigma
  bool needm = (v2 - v1) <= 10.0f;
  u32 cols[4];
  cols[0] = (u32)k1;
  int nr = 1;
  if(needm){
    nr = 4;
    u64 l1 = umin64(a, b), l2 = umax64(a, b);  // per-lane sorted pair; repeated extract-min
    #pragma unroll
    for(int it = 0; it < 4; it++){
      u64 mn = l1;
      #pragma unroll
      for(int m = 1; m < 64; m <<= 1){ u64 o = __shfl_xor(mn, m, 64); mn = umin64(mn, o); }
      cols[it] = (u32)mn;
      if(l1 == mn){ l1 = l2; l2 = ~0ull; }
    }
  }

  // f row in registers (exact fp32): c = lane*16 + j
  float fv[16];
  {
    const float4* fp = (const float4*)(fT + (size_t)n * CDIM) + lane * 4;
    #pragma unroll
    for(int q = 0; q < 4; q++){
      float4 v = fp[q];
      fv[q*4+0] = v.x; fv[q*4+1] = v.y; fv[q*4+2] = v.z; fv[q*4+3] = v.w;
    }
  }
  float fs = 0.f;
  #pragma unroll
  for(int j = 0; j < 16; j++) fs += fv[j] * fv[j];
  fs = wave_sum(fs);

  float bestd = 1e30f; int bestc = 0x7fffffff;
  for(int i = 0; i < nr; ++i){              // wave-uniform trip count
    int c = (int)cols[i];
    const float4* mrow = (const float4*)(mb + (size_t)c * CDIM) + lane * 4;
    float p = 0.f;
    #pragma unroll
    for(int q = 0; q < 4; q++){
      float4 mv = mrow[q];
      p += fv[q*4+0]*mv.x + fv[q*4+1]*mv.y + fv[q*4+2]*mv.z + fv[q*4+3]*mv.w;
    }
    p = wave_sum(p);
    float d = sqrtf(fmaxf(fs + m_sq[c] - 2.f * p, 0.f) + 1e-8f);
    if(d < bestd || (d == bestd && c < bestc)){ bestd = d; bestc = c; }
  }
  // influence vs the chosen nearest row (re-read; L2/L3-hot)
  {
    const float4* mrow = (const float4*)(mb + (size_t)bestc * CDIM) + lane * 4;
    float pa = 0.f;
    #pragma unroll
    for(int q = 0; q < 4; q++){
      float4 mv = mrow[q];
      pa += fabsf(fv[q*4+0]-mv.x) + fabsf(fv[q*4+1]-mv.y) + fabsf(fv[q*4+2]-mv.z) + fabsf(fv[q*4+3]-mv.w);
    }
    pa = wave_sum(pa);
    if(lane == 0){
      float inf = pa / (1024.0f * (bestd + 1e-8f));
      inf_arr[n] = inf;
      atomicMin(&minmax[0], __float_as_uint(inf));   // inf >= 0 -> bit order == float order
      atomicMax(&minmax[1], __float_as_uint(inf));
    }
  }
}

// ---- K7 (fused maps+noise): noised = features + noise * std, float4 both sides;
//      c0==0 blocks also emit the influence/noise_std maps ----
__global__ __launch_bounds__(256) void k_noise(const float* __restrict__ feat, const float* __restrict__ noise,
                                               const float* __restrict__ inf_arr, const u32* __restrict__ minmax,
                                               float* __restrict__ out){
  __shared__ float tile[64][65];
  __shared__ float ns[64];
  int b = blockIdx.z, c0 = blockIdx.y * 64, hw0 = blockIdx.x * 64;
  int t = threadIdx.x;
  if(t < 64){
    int n = b * 1024 + hw0 + t;
    float imin = __uint_as_float(minmax[0]);
    float imax = __uint_as_float(minmax[1]);
    float denom = imax - imin;
    float x = inf_arr[n];
    float norm = (denom > 1e-8f) ? ((x - imin) / fmaxf(denom, 1e-8f)) : 0.0f;
    float nsv = 0.01f + norm * 0.49f;
    ns[t] = nsv;
    if(c0 == 0){
      out[8388608 + n] = norm;       // influence_map
      out[8396800 + n] = nsv;        // noise_std_map
    }
  }
  // load: noise[n=hw][c] float4 over c -> tile[c][hw]
  #pragma unroll 4
  for(int r = 0; r < 4; r++){
    int li = r * 256 + t;              // 0..1023
    int j = li >> 4, q = li & 15;      // hw row, c-quad
    float4 v = *((const float4*)(noise + ((size_t)(b * 1024 + hw0 + j)) * CDIM + c0) + q);
    tile[q * 4 + 0][j] = v.x; tile[q * 4 + 1][j] = v.y;
    tile[q * 4 + 2][j] = v.z; tile[q * 4 + 3][j] = v.w;
  }
  __syncthreads();
  // store: out[c][hw] = feat + noise^T * ns, float4 over hw
  #pragma unroll 4
  for(int r = 0; r < 4; r++){
    int li = r * 256 + t;
    int i = li >> 4, h4 = li & 15;     // c offset, hw-quad
    size_t idx = ((size_t)b * CDIM + c0 + i) * 1024 + hw0 + h4 * 4;
    float4 f = *(const float4*)(feat + idx);
    float4 o;
    o.x = f.x + tile[i][h4 * 4 + 0] * ns[h4 * 4 + 0];
    o.y = f.y + tile[i][h4 * 4 + 1] * ns[h4 * 4 + 1];
    o.z = f.z + tile[i][h4 * 4 + 2] * ns[h4 * 4 + 2];
    o.w = f.w + tile[i][h4 * 4 + 3] * ns[h4 * 4 + 3];
    *(float4*)(out + idx) = o;
  }
}

extern "C" void kernel_launch(void* const* d_in, const int* in_sizes, int n_in,
                              void* d_out, int out_size, void* d_ws, size_t ws_size,
                              hipStream_t stream){
  const float* features = (const float*)d_in[0];
  const float* mb       = (const float*)d_in[1];
  const float* noise    = (const float*)d_in[2];
  float* out = (float*)d_out;
  char* ws = (char*)d_ws;

  // fT (32MB exact fp32 transposed features) lives in d_out's noised region; overwritten last.
  float* fT = (float*)d_out;

  size_t off = 0;
  signed char* mq = (signed char*)(ws + off); off += (size_t)MROW * CDIM;   // 16MB
  signed char* fq = (signed char*)(ws + off); off += (size_t)NPOS * CDIM;   // 8MB
  float* m_sq    = (float*)(ws + off); off += (size_t)MROW * 4;
  float* inf_arr = (float*)(ws + off); off += (size_t)NPOS * 4;
  u32* minmax    = (u32*)(ws + off);   off += 256;
  u64* cand      = (u64*)(ws + off);   off += (size_t)NPOS * 128 * 8;       // 8MB

  k_prep<<<4096 + 2048, 256, 0, stream>>>(mb, features, mq, fq, fT, m_sq, minmax);
  k_gemm<<<dim3(2048), 512, 0, stream>>>(fq, mq, m_sq, cand);
  k_finalize<<<2048, 256, 0, stream>>>(cand, fT, mb, m_sq, inf_arr, minmax);
  k_noise<<<dim3(16, 16, 8), 256, 0, stream>>>(features, noise, inf_arr, minmax, out);
}

// Round 15
// 463.785 us; speedup vs baseline: 1.3042x; 1.3042x over previous
//
#include <hip/hip_runtime.h>
#include <stdint.h>
#include <stddef.h>

typedef unsigned short u16;
typedef unsigned int u32;
typedef unsigned long long u64;
typedef __attribute__((ext_vector_type(4))) int i32x4;
typedef __attribute__((ext_vector_type(4))) float f32x4;

#define NPOS 8192      // B*H*W
#define MROW 16384     // M
#define CDIM 1024      // C
#define QS 25.4f       // int8 quant scale (clip at ~5 sigma: essentially never)

__device__ __forceinline__ u32 fkey(float f){   // order-preserving float->uint
  union { float f; u32 u; } z; z.f = f;
  u32 b = z.u;
  return b ^ ((b & 0x80000000u) ? 0xffffffffu : 0x80000000u);
}
__device__ __forceinline__ float unfkey(u32 u){
  u32 b = (u & 0x80000000u) ? (u ^ 0x80000000u) : ~u;
  union { u32 u; float f; } z; z.u = b; return z.f;
}
__device__ __forceinline__ u64 umin64(u64 a, u64 b){ return a < b ? a : b; }
__device__ __forceinline__ u64 umax64(u64 a, u64 b){ return a > b ? a : b; }
__device__ __forceinline__ float wave_sum(float v){
  #pragma unroll
  for(int o = 32; o; o >>= 1) v += __shfl_xor(v, o, 64);
  return v;
}
__device__ __forceinline__ int q8(float x){     // signed i8 code, low 8 bits
  float y = fminf(fmaxf(x * QS, -127.f), 127.f);
  return __float2int_rn(y) & 0xff;
}

// async global->LDS, 16B per lane (wave-uniform LDS base + lane*16; global addr is per-lane)
__device__ __forceinline__ void gload16(const void* g, void* l){
  __builtin_amdgcn_global_load_lds((const __attribute__((address_space(1))) u32*)g,
                                   (__attribute__((address_space(3))) u32*)l, 16, 0, 0);
}

// ---- K1 (fused prep): blocks [0,4096): 4 mb rows per block, wave-per-row -> mq i8 + m_sq;
//      blocks [4096, 6144): feature transpose -> fT (N,C) fp32 + fq (N,C) i8, float4 both sides ----
__global__ __launch_bounds__(256) void k_prep(const float* __restrict__ mb, const float* __restrict__ feat,
                                              signed char* __restrict__ mq, signed char* __restrict__ fq,
                                              float* __restrict__ fT, float* __restrict__ m_sq,
                                              u32* __restrict__ minmax){
  __shared__ float tile[64][65];
  int bid = blockIdx.x, t = threadIdx.x;
  if(bid < 4096){
    int lane = t & 63, w = t >> 6;
    int row = bid * 4 + w;
    if(row == 0 && lane == 0){ minmax[0] = 0x7f800000u; minmax[1] = 0u; }
    const float4* src = (const float4*)(mb + (size_t)row * CDIM);
    u32* dst = (u32*)(mq + (size_t)row * CDIM);
    float s = 0.f;
    #pragma unroll
    for(int ch = 0; ch < 4; ch++){
      float4 v = src[ch * 64 + lane];
      u32 packed = (u32)q8(v.x) | ((u32)q8(v.y) << 8) | ((u32)q8(v.z) << 16) | ((u32)q8(v.w) << 24);
      dst[ch * 64 + lane] = packed;
      s += v.x*v.x + v.y*v.y + v.z*v.z + v.w*v.w;
    }
    s = wave_sum(s);
    if(lane == 0) m_sq[row] = s;
  } else {
    int e = bid - 4096;                 // 0..2047
    int b = e >> 8, c0 = ((e >> 4) & 15) * 64, hw0 = (e & 15) * 64;
    // load: feat[b][c0+cL][hw0+quad] -> tile[cL][hw] (float4 over hw, coalesced)
    #pragma unroll 4
    for(int r = 0; r < 4; r++){
      int li = r * 256 + t;             // 0..1023
      int cL = li >> 4, q = li & 15;
      float4 v = *((const float4*)(feat + ((size_t)b * CDIM + c0 + cL) * 1024 + hw0) + q);
      tile[cL][q * 4 + 0] = v.x; tile[cL][q * 4 + 1] = v.y;
      tile[cL][q * 4 + 2] = v.z; tile[cL][q * 4 + 3] = v.w;
    }
    __syncthreads();
    // store: fT[n][c] float4 over c + fq packed u32 (both coalesced)
    #pragma unroll 4
    for(int r = 0; r < 4; r++){
      int li = r * 256 + t;
      int hwL = li >> 4, q = li & 15;
      float4 v;
      v.x = tile[q * 4 + 0][hwL]; v.y = tile[q * 4 + 1][hwL];
      v.z = tile[q * 4 + 2][hwL]; v.w = tile[q * 4 + 3][hwL];
      int n = b * 1024 + hw0 + hwL;
      int c = c0 + q * 4;
      *((float4*)(fT + (size_t)n * CDIM + c)) = v;
      u32 packed = (u32)q8(v.x) | ((u32)q8(v.y) << 8) | ((u32)q8(v.z) << 16) | ((u32)q8(v.w) << 24);
      *((u32*)(fq + (size_t)n * CDIM + c)) = packed;
    }
  }
}

__device__ __forceinline__ i32x4 mfma16_i8(i32x4 a, i32x4 b, i32x4 c){
  return __builtin_amdgcn_mfma_i32_16x16x64_i8(a, b, c, 0, 0, 0);
}

// ---- K4 (best measured, R13): int8 GEMM, 256x256 tile, 8 waves (2x4), per-wave 128x64,
//          BK=128 (i8), 2 LDS buffers (128KB), 8 sync-drains. 128B rows = 8 slots of 16B;
//          slot s holds k-block s^(row&7); frag read slot (kc*4+kg)^(fr&7) -> conflict-free.
//          Four schedule variants (R7/R9/R11/R13) all converge to ~253us = structural
//          limit at 2 waves/SIMD with a 128-reg accumulator. ----
__global__ __launch_bounds__(512, 2) void k_gemm(const signed char* __restrict__ fq, const signed char* __restrict__ mq,
                                                 const float* __restrict__ m_sq, u64* __restrict__ cand){
  __shared__ unsigned char lds[2][2][256][128];   // 128 KB
  int bid = blockIdx.x;
  int ct = (bid & 7) * 8 + ((bid >> 3) & 7);   // XCD-chunked: XCD k owns ct in [8k, 8k+8)
  int rt = bid >> 6;                           // 0..31
  int t = threadIdx.x, lane = t & 63, wid = t >> 6;
  int wm = wid >> 2, wn = wid & 3;        // wave tile: rows wm*128, cols wn*64
  int fr = lane & 15, kg = lane >> 4;     // fragment row sel / k-slot sel (16 i8 each)
  int sr = t >> 3, sl = t & 7;            // staging: 8 slots per 128B row, 64 rows per round

  // loop-carried global staging pointers (advance +128 per staged K-tile)
  int ssw = (sl ^ (sr & 7)) * 16;         // inverse swizzle on SOURCE ((sr+64k)&7 == sr&7)
  const signed char* pA = fq + (size_t)(rt * 256 + sr) * CDIM + ssw;
  const signed char* pB = mq + (size_t)(ct * 256 + sr) * CDIM + ssw;
  unsigned char* Ld = &lds[0][0][sr][sl * 16];          // buf adds literal b*65536; B adds 32768
  // thread-constant fragment slot offsets for the two k-chunks (kc=0,1) of BK=128
  int fsw0 = ((0 + kg) ^ (fr & 7)) * 16;
  int fsw1 = ((4 + kg) ^ (fr & 7)) * 16;
  const unsigned char* La = &lds[0][0][wm * 128 + fr][0];   // A: + mi*2048 + fsw
  const unsigned char* Lb = &lds[0][1][wn * 64  + fr][0];   // B: + ni*2048 + fsw

  const i32x4 zero = {0, 0, 0, 0};
  i32x4 acc[8][4];
  #pragma unroll
  for(int i = 0; i < 8; i++)
    #pragma unroll
    for(int j = 0; j < 4; j++) acc[i][j] = zero;

#define STAGE(BUF) do{ \
    _Pragma("unroll") for(int r_ = 0; r_ < 4; r_++) \
      gload16(pA + (size_t)(r_ * 64) * CDIM, Ld + (BUF) * 65536 + r_ * 8192); \
    _Pragma("unroll") for(int r_ = 0; r_ < 4; r_++) \
      gload16(pB + (size_t)(r_ * 64) * CDIM, Ld + (BUF) * 65536 + 32768 + r_ * 8192); \
    pA += 128; pB += 128; \
  }while(0)

#define HALF(BUF, FS) do{ \
    i32x4 fb[4]; \
    _Pragma("unroll") for(int ni_ = 0; ni_ < 4; ni_++) \
      fb[ni_] = *(const i32x4*)(Lb + (BUF) * 65536 + ni_ * 2048 + (FS)); \
    _Pragma("unroll") for(int mi_ = 0; mi_ < 8; mi_++){ \
      i32x4 fa = *(const i32x4*)(La + (BUF) * 65536 + mi_ * 2048 + (FS)); \
      _Pragma("unroll") for(int ni_ = 0; ni_ < 4; ni_++) \
        acc[mi_][ni_] = mfma16_i8(fa, fb[ni_], acc[mi_][ni_]); \
    } \
  }while(0)

#define COMPUTE(BUF) do{ HALF(BUF, fsw0); HALF(BUF, fsw1); }while(0)
#define SYNC0() asm volatile("s_waitcnt vmcnt(0) lgkmcnt(0)\n\ts_barrier" ::: "memory")

  STAGE(0);
  SYNC0();
  for(int it = 0; it < 3; ++it){
    STAGE(1); COMPUTE(0); SYNC0();
    STAGE(0); COMPUTE(1); SYNC0();
  }
  STAGE(1); COMPUTE(0); SYNC0();   // K-tile 6 (stage tile 7)
  COMPUTE(1);                      // K-tile 7

#undef STAGE
#undef HALF
#undef COMPUTE
#undef SYNC0

  // ---- epilogue: per-row TOP-2 of (m_sq[col] - 2*cross) over this block's 256 cols ----
  const float SI = 2.0f / (QS * QS);
  float msq[4];
  #pragma unroll
  for(int ni = 0; ni < 4; ni++) msq[ni] = m_sq[ct * 256 + wn * 64 + ni * 16 + fr];
  __syncthreads();                          // all LDS reads done; safe to reuse as scratch
  u64* rl = (u64*)&lds[0][0][0][0];         // [wn][256 rows][2] = 16KB
  #pragma unroll
  for(int mi = 0; mi < 8; mi++){
    #pragma unroll
    for(int j = 0; j < 4; j++){
      u64 k1 = ~0ull, k2 = ~0ull;
      #pragma unroll
      for(int ni = 0; ni < 4; ni++){
        float v = msq[ni] - SI * (float)acc[mi][ni][j];
        u64 key = ((u64)fkey(v) << 32) | (u32)(ct * 256 + wn * 64 + ni * 16 + fr);
        if(key < k1){ k2 = k1; k1 = key; } else if(key < k2){ k2 = key; }
      }
      #pragma unroll
      for(int m = 1; m < 16; m <<= 1){      // butterfly top-2 merge over the 16 fr-lanes
        u64 o1 = __shfl_xor(k1, m, 64), o2 = __shfl_xor(k2, m, 64);
        u64 n1 = umin64(k1, o1);
        u64 n2 = umin64(umax64(k1, o1), umin64(k2, o2));
        k1 = n1; k2 = n2;
      }
      if(fr == 0){
        int rowl = wm * 128 + mi * 16 + kg * 4 + j;
        rl[(wn * 256 + rowl) * 2 + 0] = k1;
        rl[(wn * 256 + rowl) * 2 + 1] = k2;
      }
    }
  }
  __syncthreads();
  if(t < 256){
    u64 a1 = rl[t * 2], a2 = rl[t * 2 + 1];
    #pragma unroll
    for(int w = 1; w < 4; w++){
      u64 b1 = rl[(w * 256 + t) * 2], b2 = rl[(w * 256 + t) * 2 + 1];
      u64 n1 = umin64(a1, b1);
      u64 n2 = umin64(umax64(a1, b1), umin64(a2, b2));
      a1 = n1; a2 = n2;
    }
    size_t base = ((size_t)(rt * 256 + t)) * 128 + ct * 2;
    cand[base] = a1; cand[base + 1] = a2;
  }
}

// ---- K5: wave-per-row finalize, zero barriers. Top-2/top-4 of 128 keys via u64 wave
//          butterflies; exact fp32 recheck (1 or 4 cands by margin); influence ----
__global__ __launch_bounds__(256) void k_finalize(const u64* __restrict__ cand,
    const float* __restrict__ fT,
    const float* __restrict__ mb, const float* __restrict__ m_sq,
    float* __restrict__ inf_arr, u32* __restrict__ minmax){
  int t = threadIdx.x, lane = t & 63, w = t >> 6;
  int n = blockIdx.x * 4 + w;
  const u64* cr = cand + (size_t)n * 128;
  u64 a = cr[lane * 2], b = cr[lane * 2 + 1];
  u64 k1 = umin64(a, b), k2 = umax64(a, b);
  #pragma unroll
  for(int m = 1; m < 64; m <<= 1){          // wave butterfly top-2 merge (all lanes converge)
    u64 o1 = __shfl_xor(k1, m, 64), o2 = __shfl_xor(k2, m, 64);
    u64 n1 = umin64(k1, o1);
    u64 n2 = umin64(umax64(k1, o1), umin64(k2, o2));
    k1 = n1; k2 = n2;
  }
  float v1 = unfkey((u32)(k1 >> 32)), v2 = unfkey((u32)(k2 >> 32));
  // margin: approx-dist2 gap; i8 quant err sigma ~1.46 pairwise -> 10 is ~6.8 sigma
  bool needm = (v2 - v1) <= 10.0f;
  u32 cols[4];
  cols[0] = (u32)k1;
  int nr = 1;
  if(needm){
    nr = 4;
    u64 l1 = umin64(a, b), l2 = umax64(a, b);  // per-lane sorted pair; repeated extract-min
    #pragma unroll
    for(int it = 0; it < 4; it++){
      u64 mn = l1;
      #pragma unroll
      for(int m = 1; m < 64; m <<= 1){ u64 o = __shfl_xor(mn, m, 64); mn = umin64(mn, o); }
      cols[it] = (u32)mn;
      if(l1 == mn){ l1 = l2; l2 = ~0ull; }
    }
  }

  // f row in registers (exact fp32): c = lane*16 + j
  float fv[16];
  {
    const float4* fp = (const float4*)(fT + (size_t)n * CDIM) + lane * 4;
    #pragma unroll
    for(int q = 0; q < 4; q++){
      float4 v = fp[q];
      fv[q*4+0] = v.x; fv[q*4+1] = v.y; fv[q*4+2] = v.z; fv[q*4+3] = v.w;
    }
  }
  float fs = 0.f;
  #pragma unroll
  for(int j = 0; j < 16; j++) fs += fv[j] * fv[j];
  fs = wave_sum(fs);

  float bestd = 1e30f; int bestc = 0x7fffffff;
  for(int i = 0; i < nr; ++i){              // wave-uniform trip count
    int c = (int)cols[i];
    const float4* mrow = (const float4*)(mb + (size_t)c * CDIM) + lane * 4;
    float p = 0.f;
    #pragma unroll
    for(int q = 0; q < 4; q++){
      float4 mv = mrow[q];
      p += fv[q*4+0]*mv.x + fv[q*4+1]*mv.y + fv[q*4+2]*mv.z + fv[q*4+3]*mv.w;
    }
    p = wave_sum(p);
    float d = sqrtf(fmaxf(fs + m_sq[c] - 2.f * p, 0.f) + 1e-8f);
    if(d < bestd || (d == bestd && c < bestc)){ bestd = d; bestc = c; }
  }
  // influence vs the chosen nearest row (re-read; L2/L3-hot)
  {
    const float4* mrow = (const float4*)(mb + (size_t)bestc * CDIM) + lane * 4;
    float pa = 0.f;
    #pragma unroll
    for(int q = 0; q < 4; q++){
      float4 mv = mrow[q];
      pa += fabsf(fv[q*4+0]-mv.x) + fabsf(fv[q*4+1]-mv.y) + fabsf(fv[q*4+2]-mv.z) + fabsf(fv[q*4+3]-mv.w);
    }
    pa = wave_sum(pa);
    if(lane == 0){
      float inf = pa / (1024.0f * (bestd + 1e-8f));
      inf_arr[n] = inf;
      atomicMin(&minmax[0], __float_as_uint(inf));   // inf >= 0 -> bit order == float order
      atomicMax(&minmax[1], __float_as_uint(inf));
    }
  }
}

// ---- K7 (fused maps+noise): noised = features + noise * std, float4 both sides;
//      c0==0 blocks also emit the influence/noise_std maps ----
__global__ __launch_bounds__(256) void k_noise(const float* __restrict__ feat, const float* __restrict__ noise,
                                               const float* __restrict__ inf_arr, const u32* __restrict__ minmax,
                                               float* __restrict__ out){
  __shared__ float tile[64][65];
  __shared__ float ns[64];
  int b = blockIdx.z, c0 = blockIdx.y * 64, hw0 = blockIdx.x * 64;
  int t = threadIdx.x;
  if(t < 64){
    int n = b * 1024 + hw0 + t;
    float imin = __uint_as_float(minmax[0]);
    float imax = __uint_as_float(minmax[1]);
    float denom = imax - imin;
    float x = inf_arr[n];
    float norm = (denom > 1e-8f) ? ((x - imin) / fmaxf(denom, 1e-8f)) : 0.0f;
    float nsv = 0.01f + norm * 0.49f;
    ns[t] = nsv;
    if(c0 == 0){
      out[8388608 + n] = norm;       // influence_map
      out[8396800 + n] = nsv;        // noise_std_map
    }
  }
  // load: noise[n=hw][c] float4 over c -> tile[c][hw]
  #pragma unroll 4
  for(int r = 0; r < 4; r++){
    int li = r * 256 + t;              // 0..1023
    int j = li >> 4, q = li & 15;      // hw row, c-quad
    float4 v = *((const float4*)(noise + ((size_t)(b * 1024 + hw0 + j)) * CDIM + c0) + q);
    tile[q * 4 + 0][j] = v.x; tile[q * 4 + 1][j] = v.y;
    tile[q * 4 + 2][j] = v.z; tile[q * 4 + 3][j] = v.w;
  }
  __syncthreads();
  // store: out[c][hw] = feat + noise^T * ns, float4 over hw
  #pragma unroll 4
  for(int r = 0; r < 4; r++){
    int li = r * 256 + t;
    int i = li >> 4, h4 = li & 15;     // c offset, hw-quad
    size_t idx = ((size_t)b * CDIM + c0 + i) * 1024 + hw0 + h4 * 4;
    float4 f = *(const float4*)(feat + idx);
    float4 o;
    o.x = f.x + tile[i][h4 * 4 + 0] * ns[h4 * 4 + 0];
    o.y = f.y + tile[i][h4 * 4 + 1] * ns[h4 * 4 + 1];
    o.z = f.z + tile[i][h4 * 4 + 2] * ns[h4 * 4 + 2];
    o.w = f.w + tile[i][h4 * 4 + 3] * ns[h4 * 4 + 3];
    *(float4*)(out + idx) = o;
  }
}

extern "C" void kernel_launch(void* const* d_in, const int* in_sizes, int n_in,
                              void* d_out, int out_size, void* d_ws, size_t ws_size,
                              hipStream_t stream){
  const float* features = (const float*)d_in[0];
  const float* mb       = (const float*)d_in[1];
  const float* noise    = (const float*)d_in[2];
  float* out = (float*)d_out;
  char* ws = (char*)d_ws;

  // fT (32MB exact fp32 transposed features) lives in d_out's noised region; overwritten last.
  float* fT = (float*)d_out;

  size_t off = 0;
  signed char* mq = (signed char*)(ws + off); off += (size_t)MROW * CDIM;   // 16MB
  signed char* fq = (signed char*)(ws + off); off += (size_t)NPOS * CDIM;   // 8MB
  float* m_sq    = (float*)(ws + off); off += (size_t)MROW * 4;
  float* inf_arr = (float*)(ws + off); off += (size_t)NPOS * 4;
  u32* minmax    = (u32*)(ws + off);   off += 256;
  u64* cand      = (u64*)(ws + off);   off += (size_t)NPOS * 128 * 8;       // 8MB

  k_prep<<<4096 + 2048, 256, 0, stream>>>(mb, features, mq, fq, fT, m_sq, minmax);
  k_gemm<<<dim3(2048), 512, 0, stream>>>(fq, mq, m_sq, cand);
  k_finalize<<<2048, 256, 0, stream>>>(cand, fT, mb, m_sq, inf_arr, minmax);
  k_noise<<<dim3(16, 16, 8), 256, 0, stream>>>(features, noise, inf_arr, minmax, out);
}